// Round 1
// baseline (5837.063 us; speedup 1.0000x reference)
//
#include <hip/hip_runtime.h>
#include <hip/hip_bf16.h>

// Model dims: B=16, N=2048, F=40, D=256, H=8, K=256, L=4, DH=32
// All inputs fp32, output fp32 [B*N, 1].

static __device__ __forceinline__ float gelu_f(float v) {
    return 0.5f * v * (1.0f + erff(v * 0.70710678118654752f));
}

// ---------------- embed + pos + LN0 (one block per row) ----------------
__global__ __launch_bounds__(256)
void embed_ln_kernel(const float* __restrict__ x, const float* __restrict__ Wemb,
                     const float* __restrict__ bemb, const float* __restrict__ pos,
                     const float* __restrict__ g0, const float* __restrict__ b0,
                     float* __restrict__ H)
{
    __shared__ float xs[40];
    __shared__ float red[4];
    const int row = blockIdx.x;          // b*2048 + n
    const int n = row & 2047;
    const int d = threadIdx.x;
    if (d < 40) xs[d] = x[(long)row * 40 + d];
    __syncthreads();
    float v = bemb[d] + pos[(long)n * 256 + d];
    #pragma unroll 8
    for (int f = 0; f < 40; ++f) v += xs[f] * Wemb[f * 256 + d];
    // LN over the 256 values (one per thread)
    float s = v;
    #pragma unroll
    for (int m = 32; m >= 1; m >>= 1) s += __shfl_xor(s, m);
    const int wid = d >> 6;
    if ((d & 63) == 0) red[wid] = s;
    __syncthreads();
    const float mean = (red[0] + red[1] + red[2] + red[3]) * (1.0f / 256.0f);
    const float dv = v - mean;
    float q = dv * dv;
    #pragma unroll
    for (int m = 32; m >= 1; m >>= 1) q += __shfl_xor(q, m);
    __syncthreads();
    if ((d & 63) == 0) red[wid] = q;
    __syncthreads();
    const float var = (red[0] + red[1] + red[2] + red[3]) * (1.0f / 256.0f);
    H[(long)row * 256 + d] = dv * rsqrtf(var + 1e-5f) * g0[d] + b0[d];
}

// ---------------- row LayerNorm: 4 rows/block, one wave per row ----------------
__global__ __launch_bounds__(256)
void ln_kernel(const float* __restrict__ X, const float* __restrict__ g,
               const float* __restrict__ b, float* __restrict__ Y)
{
    const int row = blockIdx.x * 4 + (threadIdx.x >> 6);
    const int lane = threadIdx.x & 63;
    const long base = (long)row * 256 + lane * 4;
    float4 xv = *(const float4*)&X[base];
    float s = xv.x + xv.y + xv.z + xv.w;
    #pragma unroll
    for (int m = 32; m >= 1; m >>= 1) s += __shfl_xor(s, m);
    const float mean = s * (1.0f / 256.0f);
    const float dx = xv.x - mean, dy = xv.y - mean, dz = xv.z - mean, dw = xv.w - mean;
    float q = dx * dx + dy * dy + dz * dz + dw * dw;
    #pragma unroll
    for (int m = 32; m >= 1; m >>= 1) q += __shfl_xor(q, m);
    const float inv = rsqrtf(q * (1.0f / 256.0f) + 1e-5f);
    const float4 gv = *(const float4*)&g[lane * 4];
    const float4 bv = *(const float4*)&b[lane * 4];
    float4 y;
    y.x = dx * inv * gv.x + bv.x;
    y.y = dy * inv * gv.y + bv.y;
    y.z = dz * inv * gv.z + bv.z;
    y.w = dw * inv * gv.w + bv.w;
    *(float4*)&Y[base] = y;
}

// ---------------- generic fp32 tiled GEMM ----------------
// C[bz] (+)= op(A[bz]) @ B[bz] (+bias)(gelu)
// TA==0: A is [M,Kd] row-major (lda = row stride)
// TA==1: A stored [Kd,M] (lda = row stride of the stored matrix) -> computes A^T @ B
// Tiles: 64x64x16, 256 threads, 4x4 per thread. M,N multiples of 64; Kd multiple of 16.
template<int TA>
__global__ __launch_bounds__(256)
void gemm_f32(const float* __restrict__ A, const float* __restrict__ B,
              const float* __restrict__ bias, float* __restrict__ C,
              int M, int N, int Kd, int lda, int ldb, int ldc,
              long sA, long sB, long sC, int accum, int act)
{
    __shared__ float As[16][68];
    __shared__ float Bs[16][68];
    const int bz = blockIdx.z;
    const float* Ab = A + (long)bz * sA;
    const float* Bb = B + (long)bz * sB;
    float* Cb = C + (long)bz * sC;
    const int m0 = blockIdx.x * 64, n0 = blockIdx.y * 64;
    const int t = threadIdx.x;
    const int tx = t & 15, ty = t >> 4;
    const int idx = t * 4;
    float acc[4][4] = {};
    for (int k0 = 0; k0 < Kd; k0 += 16) {
        if (TA == 0) {
            const int r = idx >> 4, c = idx & 15;
            float4 av = *(const float4*)&Ab[(long)(m0 + r) * lda + k0 + c];
            As[c + 0][r] = av.x; As[c + 1][r] = av.y; As[c + 2][r] = av.z; As[c + 3][r] = av.w;
        } else {
            const int kk = idx >> 6, mm = idx & 63;
            float4 av = *(const float4*)&Ab[(long)(k0 + kk) * lda + m0 + mm];
            *(float4*)&As[kk][mm] = av;
        }
        {
            const int kk = idx >> 6, cc = idx & 63;
            float4 bv = *(const float4*)&Bb[(long)(k0 + kk) * ldb + n0 + cc];
            *(float4*)&Bs[kk][cc] = bv;
        }
        __syncthreads();
        #pragma unroll
        for (int kk = 0; kk < 16; ++kk) {
            float4 av = *(const float4*)&As[kk][ty * 4];
            float4 bv = *(const float4*)&Bs[kk][tx * 4];
            acc[0][0] += av.x * bv.x; acc[0][1] += av.x * bv.y; acc[0][2] += av.x * bv.z; acc[0][3] += av.x * bv.w;
            acc[1][0] += av.y * bv.x; acc[1][1] += av.y * bv.y; acc[1][2] += av.y * bv.z; acc[1][3] += av.y * bv.w;
            acc[2][0] += av.z * bv.x; acc[2][1] += av.z * bv.y; acc[2][2] += av.z * bv.z; acc[2][3] += av.z * bv.w;
            acc[3][0] += av.w * bv.x; acc[3][1] += av.w * bv.y; acc[3][2] += av.w * bv.z; acc[3][3] += av.w * bv.w;
        }
        __syncthreads();
    }
    float4 bv4 = make_float4(0.f, 0.f, 0.f, 0.f);
    if (bias) bv4 = *(const float4*)&bias[n0 + tx * 4];
    #pragma unroll
    for (int i = 0; i < 4; ++i) {
        const long off = (long)(m0 + ty * 4 + i) * ldc + n0 + tx * 4;
        float4 rv;
        rv.x = acc[i][0] + bv4.x; rv.y = acc[i][1] + bv4.y;
        rv.z = acc[i][2] + bv4.z; rv.w = acc[i][3] + bv4.w;
        if (act == 1) {
            rv.x = gelu_f(rv.x); rv.y = gelu_f(rv.y);
            rv.z = gelu_f(rv.z); rv.w = gelu_f(rv.w);
        }
        if (accum) {
            float4 cv = *(const float4*)&Cb[off];
            rv.x += cv.x; rv.y += cv.y; rv.z += cv.z; rv.w += cv.w;
        }
        *(float4*)&Cb[off] = rv;
    }
}

// ---------------- fused attention over low-rank K=256 ----------------
// grid (N/32, H, B), 256 threads. Q,O: [B*N, 256] (head slice), Kp,Vp: [B*256, 256].
__global__ __launch_bounds__(256)
void attn_kernel(const float* __restrict__ Q, const float* __restrict__ Kp,
                 const float* __restrict__ Vp, float* __restrict__ O)
{
    __shared__ float qs[32][33];
    __shared__ float sc[32][257];
    __shared__ float red[8][32];
    __shared__ float rowstat[32];
    const int qt = blockIdx.x, hh = blockIdx.y, b = blockIdx.z;
    const int t = threadIdx.x;
    const int n0 = qt * 32;
    // load Q tile [32 rows][32 dims]
    #pragma unroll
    for (int i = 0; i < 4; ++i) {
        const int idx = t + i * 256;
        const int r = idx >> 5, d = idx & 31;
        qs[r][d] = Q[((long)(b * 2048 + n0 + r)) * 256 + hh * 32 + d];
    }
    __syncthreads();
    const int r = t & 31, g = t >> 5;       // 8 k-groups of 32 columns
    float qreg[32];
    #pragma unroll
    for (int d = 0; d < 32; ++d) qreg[d] = qs[r][d];
    const float* kbase = Kp + ((long)(b * 256 + g * 32)) * 256 + hh * 32;
    float lmax = -1e30f;
    for (int kk = 0; kk < 32; ++kk) {
        const float* krow = kbase + kk * 256;
        float s = 0.f;
        #pragma unroll
        for (int d = 0; d < 32; d += 4) {
            float4 kv = *(const float4*)(krow + d);
            s += qreg[d] * kv.x + qreg[d + 1] * kv.y + qreg[d + 2] * kv.z + qreg[d + 3] * kv.w;
        }
        s *= 0.17677669529663687f;          // 1/sqrt(32)
        sc[r][g * 32 + kk] = s;
        lmax = fmaxf(lmax, s);
    }
    red[g][r] = lmax;
    __syncthreads();
    if (t < 32) {
        float m = red[0][t];
        #pragma unroll
        for (int j = 1; j < 8; ++j) m = fmaxf(m, red[j][t]);
        rowstat[t] = m;
    }
    __syncthreads();
    const float rmax = rowstat[r];
    float lsum = 0.f;
    for (int kk = 0; kk < 32; ++kk) {
        float e = expf(sc[r][g * 32 + kk] - rmax);
        sc[r][g * 32 + kk] = e;
        lsum += e;
    }
    red[g][r] = lsum;
    __syncthreads();
    if (t < 32) {
        float s2 = 0.f;
        #pragma unroll
        for (int j = 0; j < 8; ++j) s2 += red[j][t];
        rowstat[t] = s2;
    }
    __syncthreads();
    // O = (P @ V) / rowsum ; thread: row rr, 4 dims
    const int rr = t >> 3, dq = (t & 7) * 4;
    const float* vbase = Vp + ((long)(b * 256)) * 256 + hh * 32 + dq;
    float o0 = 0.f, o1 = 0.f, o2 = 0.f, o3 = 0.f;
    for (int kk = 0; kk < 256; ++kk) {
        const float p = sc[rr][kk];
        float4 vv = *(const float4*)(vbase + (long)kk * 256);
        o0 += p * vv.x; o1 += p * vv.y; o2 += p * vv.z; o3 += p * vv.w;
    }
    const float inv = 1.0f / rowstat[rr];
    float4 w;
    w.x = o0 * inv; w.y = o1 * inv; w.z = o2 * inv; w.w = o3 * inv;
    *(float4*)&O[((long)(b * 2048 + n0 + rr)) * 256 + hh * 32 + dq] = w;
}

// ---------------- final head: out = h @ W_out + b_out ----------------
__global__ __launch_bounds__(256)
void out_kernel(const float* __restrict__ H, const float* __restrict__ Wout,
                const float* __restrict__ bout, float* __restrict__ out)
{
    const int row = blockIdx.x * 4 + (threadIdx.x >> 6);
    const int lane = threadIdx.x & 63;
    float4 hv = *(const float4*)&H[(long)row * 256 + lane * 4];
    float4 wv = *(const float4*)&Wout[lane * 4];
    float s = hv.x * wv.x + hv.y * wv.y + hv.z * wv.z + hv.w * wv.w;
    #pragma unroll
    for (int m = 32; m >= 1; m >>= 1) s += __shfl_xor(s, m);
    if (lane == 0) out[row] = s + bout[0];
}

extern "C" void kernel_launch(void* const* d_in, const int* in_sizes, int n_in,
                              void* d_out, int out_size, void* d_ws, size_t ws_size,
                              hipStream_t stream)
{
    const float* x    = (const float*)d_in[0];
    const float* Wemb = (const float*)d_in[1];
    const float* bemb = (const float*)d_in[2];
    const float* pos  = (const float*)d_in[3];
    const float* ln0g = (const float*)d_in[4];
    const float* ln0b = (const float*)d_in[5];
    const float* ln1g = (const float*)d_in[6];
    const float* ln1b = (const float*)d_in[7];
    const float* Wq   = (const float*)d_in[8];
    const float* Wk   = (const float*)d_in[9];
    const float* Wv   = (const float*)d_in[10];
    const float* Ek   = (const float*)d_in[11];
    const float* Ev   = (const float*)d_in[12];
    const float* Wo   = (const float*)d_in[13];
    const float* bo   = (const float*)d_in[14];
    const float* ln2g = (const float*)d_in[15];
    const float* ln2b = (const float*)d_in[16];
    const float* W1   = (const float*)d_in[17];
    const float* b1   = (const float*)d_in[18];
    const float* W2   = (const float*)d_in[19];
    const float* b2   = (const float*)d_in[20];
    const float* Wout = (const float*)d_in[21];
    const float* bout = (const float*)d_in[22];

    char* ws = (char*)d_ws;
    const long BIG = 33554432L;               // 32768*256*4 bytes
    float* h   = (float*)(ws);                // persistent activations
    float* a   = (float*)(ws + BIG);          // LN output / attn output
    float* t0  = (float*)(ws + 2 * BIG);      // q / FF hidden chunk
    float* apk = (float*)(ws + 3 * BIG);      // Ek^T @ a   [B,256,256]
    float* apv = apk + 16 * 256 * 256;        // Ev^T @ a
    float* kp  = apv + 16 * 256 * 256;        // apk @ Wk
    float* vp  = kp  + 16 * 256 * 256;        // apv @ Wv
    float* outp = (float*)d_out;

    embed_ln_kernel<<<32768, 256, 0, stream>>>(x, Wemb, bemb, pos, ln0g, ln0b, h);

    for (int i = 0; i < 4; ++i) {
        const float* Wq_i = Wq + (long)i * 65536;
        const float* Wk_i = Wk + (long)i * 65536;
        const float* Wv_i = Wv + (long)i * 65536;
        const float* Wo_i = Wo + (long)i * 65536;
        const float* Ek_i = Ek + (long)i * 2048 * 256;
        const float* Ev_i = Ev + (long)i * 2048 * 256;
        const float* W1_i = W1 + (long)i * 256 * 1024;
        const float* W2_i = W2 + (long)i * 1024 * 256;

        // a = LN1(h)
        ln_kernel<<<8192, 256, 0, stream>>>(h, ln1g + i * 256, ln1b + i * 256, a);
        // q = a @ Wq
        gemm_f32<0><<<dim3(512, 4, 1), 256, 0, stream>>>(a, Wq_i, nullptr, t0,
            32768, 256, 256, 256, 256, 256, 0, 0, 0, 0, 0);
        // apk[b] = Ek^T @ a[b], apv[b] = Ev^T @ a[b]   (project to K first)
        gemm_f32<1><<<dim3(4, 4, 16), 256, 0, stream>>>(Ek_i, a, nullptr, apk,
            256, 256, 2048, 256, 256, 256, 0, 524288, 65536, 0, 0);
        gemm_f32<1><<<dim3(4, 4, 16), 256, 0, stream>>>(Ev_i, a, nullptr, apv,
            256, 256, 2048, 256, 256, 256, 0, 524288, 65536, 0, 0);
        // kp = apk @ Wk, vp = apv @ Wv
        gemm_f32<0><<<dim3(64, 4, 1), 256, 0, stream>>>(apk, Wk_i, nullptr, kp,
            4096, 256, 256, 256, 256, 256, 0, 0, 0, 0, 0);
        gemm_f32<0><<<dim3(64, 4, 1), 256, 0, stream>>>(apv, Wv_i, nullptr, vp,
            4096, 256, 256, 256, 256, 256, 0, 0, 0, 0, 0);
        // a = attention(q=t0, kp, vp)   (a is dead, reuse as O)
        attn_kernel<<<dim3(64, 8, 16), 256, 0, stream>>>(t0, kp, vp, a);
        // h += a @ Wo + bo
        gemm_f32<0><<<dim3(512, 4, 1), 256, 0, stream>>>(a, Wo_i, bo + i * 256, h,
            32768, 256, 256, 256, 256, 256, 0, 0, 0, 1, 0);
        // a = LN2(h)
        ln_kernel<<<8192, 256, 0, stream>>>(h, ln2g + i * 256, ln2b + i * 256, a);
        // FFN in 4 hidden chunks of 256: t0 = gelu(a@W1c + b1c); h += t0@W2c (+ b2 on c==0)
        for (int c = 0; c < 4; ++c) {
            gemm_f32<0><<<dim3(512, 4, 1), 256, 0, stream>>>(a, W1_i + c * 256,
                b1 + (long)i * 1024 + c * 256, t0,
                32768, 256, 256, 256, 1024, 256, 0, 0, 0, 0, 1);
            gemm_f32<0><<<dim3(512, 4, 1), 256, 0, stream>>>(t0, W2_i + (long)c * 256 * 256,
                (c == 0) ? (b2 + i * 256) : nullptr, h,
                32768, 256, 256, 256, 256, 256, 0, 0, 0, 1, 0);
        }
    }
    out_kernel<<<8192, 256, 0, stream>>>(h, Wout, bout, outp);
}

// Round 2
// 2816.866 us; speedup vs baseline: 2.0722x; 2.0722x over previous
//
#include <hip/hip_runtime.h>
#include <hip/hip_bf16.h>

// Model dims: B=16, N=2048, F=40, D=256, H=8, K=256, L=4, DH=32
// fp32 inputs/outputs; bf16 MFMA for all GEMMs, fp32 residual stream.

typedef short bf16x8 __attribute__((ext_vector_type(8)));
typedef float f32x4 __attribute__((ext_vector_type(4)));

#define GLOBAL_AS __attribute__((address_space(1)))
#define LDS_AS __attribute__((address_space(3)))

static __device__ __forceinline__ float gelu_f(float v) {
    return 0.5f * v * (1.0f + erff(v * 0.70710678118654752f));
}
static __device__ __forceinline__ ushort f2bf(float x) {
    __hip_bfloat16 h = __float2bfloat16(x);
    return __builtin_bit_cast(ushort, h);
}

// ---------------- embed + pos + LN0 (one block per row), fp32 out ----------------
__global__ __launch_bounds__(256)
void embed_ln_kernel(const float* __restrict__ x, const float* __restrict__ Wemb,
                     const float* __restrict__ bemb, const float* __restrict__ pos,
                     const float* __restrict__ g0, const float* __restrict__ b0,
                     float* __restrict__ H)
{
    __shared__ float xs[40];
    __shared__ float red[4];
    const int row = blockIdx.x;
    const int n = row & 2047;
    const int d = threadIdx.x;
    if (d < 40) xs[d] = x[(long)row * 40 + d];
    __syncthreads();
    float v = bemb[d] + pos[(long)n * 256 + d];
    #pragma unroll 8
    for (int f = 0; f < 40; ++f) v += xs[f] * Wemb[f * 256 + d];
    float s = v;
    #pragma unroll
    for (int m = 32; m >= 1; m >>= 1) s += __shfl_xor(s, m);
    const int wid = d >> 6;
    if ((d & 63) == 0) red[wid] = s;
    __syncthreads();
    const float mean = (red[0] + red[1] + red[2] + red[3]) * (1.0f / 256.0f);
    const float dv = v - mean;
    float q = dv * dv;
    #pragma unroll
    for (int m = 32; m >= 1; m >>= 1) q += __shfl_xor(q, m);
    __syncthreads();
    if ((d & 63) == 0) red[wid] = q;
    __syncthreads();
    const float var = (red[0] + red[1] + red[2] + red[3]) * (1.0f / 256.0f);
    H[(long)row * 256 + d] = dv * rsqrtf(var + 1e-5f) * g0[d] + b0[d];
}

// ---------------- LayerNorm fp32 -> bf16: 4 rows/block, wave per row ----------------
__global__ __launch_bounds__(256)
void ln_kernel(const float* __restrict__ X, const float* __restrict__ g,
               const float* __restrict__ b, ushort* __restrict__ Y)
{
    const int row = blockIdx.x * 4 + (threadIdx.x >> 6);
    const int lane = threadIdx.x & 63;
    const long base = (long)row * 256 + lane * 4;
    float4 xv = *(const float4*)&X[base];
    float s = xv.x + xv.y + xv.z + xv.w;
    #pragma unroll
    for (int m = 32; m >= 1; m >>= 1) s += __shfl_xor(s, m);
    const float mean = s * (1.0f / 256.0f);
    const float dx = xv.x - mean, dy = xv.y - mean, dz = xv.z - mean, dw = xv.w - mean;
    float q = dx * dx + dy * dy + dz * dz + dw * dw;
    #pragma unroll
    for (int m = 32; m >= 1; m >>= 1) q += __shfl_xor(q, m);
    const float inv = rsqrtf(q * (1.0f / 256.0f) + 1e-5f);
    const float4 gv = *(const float4*)&g[lane * 4];
    const float4 bv = *(const float4*)&b[lane * 4];
    ushort4 y;
    y.x = f2bf(dx * inv * gv.x + bv.x);
    y.y = f2bf(dy * inv * gv.y + bv.y);
    y.z = f2bf(dz * inv * gv.z + bv.z);
    y.w = f2bf(dw * inv * gv.w + bv.w);
    *(ushort4*)&Y[base] = y;
}

// ---------------- weight transpose + cast: in [R,C] f32 -> out [C,R] bf16 ----------------
__global__ __launch_bounds__(256)
void transpose_cast(const float* __restrict__ in, ushort* __restrict__ out,
                    int R, int C, long sIn, long sOut)
{
    __shared__ float tile[32][33];
    in += (long)blockIdx.z * sIn; out += (long)blockIdx.z * sOut;
    const int c0 = blockIdx.x * 32, r0 = blockIdx.y * 32;
    const int tx = threadIdx.x & 31, ty = threadIdx.x >> 5;
    #pragma unroll
    for (int j = 0; j < 4; ++j)
        tile[ty + j * 8][tx] = in[(long)(r0 + ty + j * 8) * C + c0 + tx];
    __syncthreads();
    #pragma unroll
    for (int j = 0; j < 4; ++j)
        out[(long)(c0 + ty + j * 8) * R + r0 + tx] = f2bf(tile[tx][ty + j * 8]);
}

// ---------------- activation transpose: abf [32768,256] -> aT [16][256][2048] ----------------
__global__ __launch_bounds__(256)
void transpose_act(const ushort* __restrict__ in, ushort* __restrict__ out)
{
    __shared__ ushort tile[32][33];
    const int c0 = blockIdx.x * 32, r0 = blockIdx.y * 32;
    const int tx = threadIdx.x & 31, ty = threadIdx.x >> 5;
    #pragma unroll
    for (int j = 0; j < 4; ++j)
        tile[ty + j * 8][tx] = in[(long)(r0 + ty + j * 8) * 256 + c0 + tx];
    __syncthreads();
    const int b = r0 >> 11, nn = r0 & 2047;
    #pragma unroll
    for (int j = 0; j < 4; ++j)
        out[((long)(b * 256 + c0 + ty + j * 8)) * 2048 + nn + tx] = tile[tx][ty + j * 8];
}

// ---------------- bf16 MFMA GEMM, m97 structure ----------------
// C[bz] = op( A[bz] @ BT[bz]^T )  — A [M,Kd] bf16, BT [N,Kd] bf16 (pre-transposed B).
// 128x128 tile, BK=32, 256 threads (4 waves, each 64x64 = 4x4 frags of 16x16x32).
template<int OBF16, int ACCUM, int ACT, int HASB>
__global__ __launch_bounds__(256)
void gemm_bf16(const ushort* __restrict__ A, const ushort* __restrict__ BT,
               const float* __restrict__ bias, void* __restrict__ Cout,
               int Kd, int lda, int ldb, int ldc,
               long sA, long sBT, long sC)
{
    __shared__ ushort Als[128 * 32];
    __shared__ ushort Bls[128 * 32];
    const int bz = blockIdx.z;
    const ushort* Ab = A + (long)bz * sA;
    const ushort* Bb = BT + (long)bz * sBT;
    const int m0 = blockIdx.x * 128, n0 = blockIdx.y * 128;
    const int t = threadIdx.x, l = t & 63, w = t >> 6;
    const int wr = w >> 1, wc = w & 1;
    const int fr = l & 15, fq = l >> 4;

    f32x4 acc[4][4];
    #pragma unroll
    for (int m = 0; m < 4; ++m)
        #pragma unroll
        for (int n = 0; n < 4; ++n) acc[m][n] = f32x4{0.f, 0.f, 0.f, 0.f};

    const int srow = t >> 2;            // staging row within 64-row chunk
    const int skcol = (t & 3) * 8;      // staging k offset
    const int dst0 = w * 512;           // ushort index: wave-uniform LDS base (lane*16B appended by HW)

    for (int kk = 0; kk < Kd; kk += 32) {
        const ushort* ag = Ab + (long)(m0 + srow) * lda + kk + skcol;
        const ushort* bg = Bb + (long)(n0 + srow) * ldb + kk + skcol;
        __builtin_amdgcn_global_load_lds((const GLOBAL_AS void*)ag,
                                         (LDS_AS void*)&Als[dst0], 16, 0, 0);
        __builtin_amdgcn_global_load_lds((const GLOBAL_AS void*)(ag + (long)64 * lda),
                                         (LDS_AS void*)&Als[2048 + dst0], 16, 0, 0);
        __builtin_amdgcn_global_load_lds((const GLOBAL_AS void*)bg,
                                         (LDS_AS void*)&Bls[dst0], 16, 0, 0);
        __builtin_amdgcn_global_load_lds((const GLOBAL_AS void*)(bg + (long)64 * ldb),
                                         (LDS_AS void*)&Bls[2048 + dst0], 16, 0, 0);
        __syncthreads();
        bf16x8 af[4], bfv[4];
        #pragma unroll
        for (int m = 0; m < 4; ++m)
            af[m] = *(const bf16x8*)&Als[(wr * 64 + m * 16 + fr) * 32 + fq * 8];
        #pragma unroll
        for (int n = 0; n < 4; ++n)
            bfv[n] = *(const bf16x8*)&Bls[(wc * 64 + n * 16 + fr) * 32 + fq * 8];
        #pragma unroll
        for (int m = 0; m < 4; ++m)
            #pragma unroll
            for (int n = 0; n < 4; ++n)
                acc[m][n] = __builtin_amdgcn_mfma_f32_16x16x32_bf16(af[m], bfv[n], acc[m][n], 0, 0, 0);
        __syncthreads();
    }

    float bsv[4] = {0.f, 0.f, 0.f, 0.f};
    if (HASB) {
        #pragma unroll
        for (int n = 0; n < 4; ++n) bsv[n] = bias[n0 + wc * 64 + n * 16 + fr];
    }
    #pragma unroll
    for (int m = 0; m < 4; ++m) {
        #pragma unroll
        for (int r = 0; r < 4; ++r) {
            const int grow = m0 + wr * 64 + m * 16 + fq * 4 + r;
            const long rowoff = (long)grow * ldc + n0 + wc * 64 + fr;
            #pragma unroll
            for (int n = 0; n < 4; ++n) {
                float v = acc[m][n][r] + bsv[n];
                if (ACT) v = gelu_f(v);
                const long off = rowoff + n * 16;
                if (OBF16) {
                    ((ushort*)Cout)[(long)bz * sC + off] = f2bf(v);
                } else {
                    float* Cp = (float*)Cout + (long)bz * sC;
                    if (ACCUM) v += Cp[off];
                    Cp[off] = v;
                }
            }
        }
    }
}

// ---------------- fused attention (fp32 VALU), bf16 out ----------------
__global__ __launch_bounds__(256)
void attn_kernel(const float* __restrict__ Q, const float* __restrict__ Kp,
                 const float* __restrict__ Vp, ushort* __restrict__ O)
{
    __shared__ float qs[32][33];
    __shared__ float sc[32][257];
    __shared__ float red[8][32];
    __shared__ float rowstat[32];
    const int qt = blockIdx.x, hh = blockIdx.y, b = blockIdx.z;
    const int t = threadIdx.x;
    const int n0 = qt * 32;
    #pragma unroll
    for (int i = 0; i < 4; ++i) {
        const int idx = t + i * 256;
        const int r = idx >> 5, d = idx & 31;
        qs[r][d] = Q[((long)(b * 2048 + n0 + r)) * 256 + hh * 32 + d];
    }
    __syncthreads();
    const int r = t & 31, g = t >> 5;
    float qreg[32];
    #pragma unroll
    for (int d = 0; d < 32; ++d) qreg[d] = qs[r][d];
    const float* kbase = Kp + ((long)(b * 256 + g * 32)) * 256 + hh * 32;
    float lmax = -1e30f;
    for (int kk = 0; kk < 32; ++kk) {
        const float* krow = kbase + kk * 256;
        float s = 0.f;
        #pragma unroll
        for (int d = 0; d < 32; d += 4) {
            float4 kv = *(const float4*)(krow + d);
            s += qreg[d] * kv.x + qreg[d + 1] * kv.y + qreg[d + 2] * kv.z + qreg[d + 3] * kv.w;
        }
        s *= 0.17677669529663687f;
        sc[r][g * 32 + kk] = s;
        lmax = fmaxf(lmax, s);
    }
    red[g][r] = lmax;
    __syncthreads();
    if (t < 32) {
        float m = red[0][t];
        #pragma unroll
        for (int j = 1; j < 8; ++j) m = fmaxf(m, red[j][t]);
        rowstat[t] = m;
    }
    __syncthreads();
    const float rmax = rowstat[r];
    float lsum = 0.f;
    for (int kk = 0; kk < 32; ++kk) {
        float e = expf(sc[r][g * 32 + kk] - rmax);
        sc[r][g * 32 + kk] = e;
        lsum += e;
    }
    red[g][r] = lsum;
    __syncthreads();
    if (t < 32) {
        float s2 = 0.f;
        #pragma unroll
        for (int j = 0; j < 8; ++j) s2 += red[j][t];
        rowstat[t] = s2;
    }
    __syncthreads();
    const int rr = t >> 3, dq = (t & 7) * 4;
    const float* vbase = Vp + ((long)(b * 256)) * 256 + hh * 32 + dq;
    float o0 = 0.f, o1 = 0.f, o2 = 0.f, o3 = 0.f;
    for (int kk = 0; kk < 256; ++kk) {
        const float p = sc[rr][kk];
        float4 vv = *(const float4*)(vbase + (long)kk * 256);
        o0 += p * vv.x; o1 += p * vv.y; o2 += p * vv.z; o3 += p * vv.w;
    }
    const float inv = 1.0f / rowstat[rr];
    ushort4 w4;
    w4.x = f2bf(o0 * inv); w4.y = f2bf(o1 * inv);
    w4.z = f2bf(o2 * inv); w4.w = f2bf(o3 * inv);
    *(ushort4*)&O[((long)(b * 2048 + n0 + rr)) * 256 + hh * 32 + dq] = w4;
}

// ---------------- final head ----------------
__global__ __launch_bounds__(256)
void out_kernel(const float* __restrict__ H, const float* __restrict__ Wout,
                const float* __restrict__ bout, float* __restrict__ out)
{
    const int row = blockIdx.x * 4 + (threadIdx.x >> 6);
    const int lane = threadIdx.x & 63;
    float4 hv = *(const float4*)&H[(long)row * 256 + lane * 4];
    float4 wv = *(const float4*)&Wout[lane * 4];
    float s = hv.x * wv.x + hv.y * wv.y + hv.z * wv.z + hv.w * wv.w;
    #pragma unroll
    for (int m = 32; m >= 1; m >>= 1) s += __shfl_xor(s, m);
    if (lane == 0) out[row] = s + bout[0];
}

extern "C" void kernel_launch(void* const* d_in, const int* in_sizes, int n_in,
                              void* d_out, int out_size, void* d_ws, size_t ws_size,
                              hipStream_t stream)
{
    const float* x    = (const float*)d_in[0];
    const float* Wemb = (const float*)d_in[1];
    const float* bemb = (const float*)d_in[2];
    const float* pos  = (const float*)d_in[3];
    const float* ln0g = (const float*)d_in[4];
    const float* ln0b = (const float*)d_in[5];
    const float* ln1g = (const float*)d_in[6];
    const float* ln1b = (const float*)d_in[7];
    const float* Wq   = (const float*)d_in[8];
    const float* Wk   = (const float*)d_in[9];
    const float* Wv   = (const float*)d_in[10];
    const float* Ek   = (const float*)d_in[11];
    const float* Ev   = (const float*)d_in[12];
    const float* Wo   = (const float*)d_in[13];
    const float* bo   = (const float*)d_in[14];
    const float* ln2g = (const float*)d_in[15];
    const float* ln2b = (const float*)d_in[16];
    const float* W1   = (const float*)d_in[17];
    const float* b1   = (const float*)d_in[18];
    const float* W2   = (const float*)d_in[19];
    const float* b2   = (const float*)d_in[20];
    const float* Wout = (const float*)d_in[21];
    const float* bout = (const float*)d_in[22];

    char* ws = (char*)d_ws;
    float*  h    = (float*)(ws + 0);                    // 33,554,432 B
    ushort* abf  = (ushort*)(ws + 33554432L);           // 16,777,216 B  [32768,256] bf16
    ushort* aT   = (ushort*)(ws + 50331648L);           // 16,777,216 B  [16][256][2048] bf16
    float*  qbuf = (float*)(ws + 67108864L);            // 33,554,432 B  q f32 / hidden bf16 [32768,512]
    ushort* apkv = (ushort*)(ws + 100663296L);          //  4,194,304 B  [16][512][256] bf16
    float*  kp   = (float*)(ws + 104857600L);           //  4,194,304 B  [16][256][256] f32
    float*  vp   = (float*)(ws + 109051904L);           //  4,194,304 B
    ushort* WT   = (ushort*)(ws + 113246208L);          // 14,680,064 B
    ushort* WqT  = WT;                                  // [4][256][256]
    ushort* WkT  = WT + 262144;
    ushort* WvT  = WT + 524288;
    ushort* WoT  = WT + 786432;
    ushort* W1T  = WT + 1048576;                        // [4][1024][256]
    ushort* W2T  = WT + 2097152;                        // [4][256][1024]
    ushort* EkvT = WT + 3145728;                        // [4][512][2048] (Ek rows 0..255, Ev rows 256..511)
    float* outp = (float*)d_out;

    // ---- weight preprocessing (transpose + cast to bf16) ----
    transpose_cast<<<dim3(8, 8, 4), 256, 0, stream>>>(Wq, WqT, 256, 256, 65536, 65536);
    transpose_cast<<<dim3(8, 8, 4), 256, 0, stream>>>(Wk, WkT, 256, 256, 65536, 65536);
    transpose_cast<<<dim3(8, 8, 4), 256, 0, stream>>>(Wv, WvT, 256, 256, 65536, 65536);
    transpose_cast<<<dim3(8, 8, 4), 256, 0, stream>>>(Wo, WoT, 256, 256, 65536, 65536);
    transpose_cast<<<dim3(32, 8, 4), 256, 0, stream>>>(W1, W1T, 256, 1024, 262144, 262144);
    transpose_cast<<<dim3(8, 32, 4), 256, 0, stream>>>(W2, W2T, 1024, 256, 262144, 262144);
    transpose_cast<<<dim3(8, 64, 4), 256, 0, stream>>>(Ek, EkvT, 2048, 256, 524288, 1048576);
    transpose_cast<<<dim3(8, 64, 4), 256, 0, stream>>>(Ev, EkvT + 524288, 2048, 256, 524288, 1048576);

    embed_ln_kernel<<<32768, 256, 0, stream>>>(x, Wemb, bemb, pos, ln0g, ln0b, h);

    for (int i = 0; i < 4; ++i) {
        const ushort* WqT_i = WqT + i * 65536;
        const ushort* WkT_i = WkT + i * 65536;
        const ushort* WvT_i = WvT + i * 65536;
        const ushort* WoT_i = WoT + i * 65536;
        const ushort* W1T_i = W1T + i * 262144;
        const ushort* W2T_i = W2T + i * 262144;
        const ushort* EkvT_i = EkvT + (long)i * 1048576;

        // a = LN1(h) -> bf16 ; aT = transpose(a)
        ln_kernel<<<8192, 256, 0, stream>>>(h, ln1g + i * 256, ln1b + i * 256, abf);
        transpose_act<<<dim3(8, 1024), 256, 0, stream>>>(abf, aT);
        // q = a @ Wq  (f32 out)
        gemm_bf16<0,0,0,0><<<dim3(256, 2, 1), 256, 0, stream>>>(abf, WqT_i, nullptr, qbuf,
            256, 256, 256, 256, 0, 0, 0);
        // apkv[b] = [Ek^T; Ev^T] @ a[b]  (bf16 out)
        gemm_bf16<1,0,0,0><<<dim3(4, 2, 16), 256, 0, stream>>>(EkvT_i, aT, nullptr, apkv,
            2048, 2048, 2048, 256, 0, 524288, 131072);
        // kp[b] = apk[b] @ Wk, vp[b] = apv[b] @ Wv  (f32 out)
        gemm_bf16<0,0,0,0><<<dim3(2, 2, 16), 256, 0, stream>>>(apkv, WkT_i, nullptr, kp,
            256, 256, 256, 256, 131072, 0, 65536);
        gemm_bf16<0,0,0,0><<<dim3(2, 2, 16), 256, 0, stream>>>(apkv + 65536, WvT_i, nullptr, vp,
            256, 256, 256, 256, 131072, 0, 65536);
        // attn -> abf (bf16)
        attn_kernel<<<dim3(64, 8, 16), 256, 0, stream>>>(qbuf, kp, vp, abf);
        // h += attnout @ Wo + bo
        gemm_bf16<0,1,0,1><<<dim3(256, 2, 1), 256, 0, stream>>>(abf, WoT_i, bo + i * 256, h,
            256, 256, 256, 256, 0, 0, 0);
        // a = LN2(h)
        ln_kernel<<<8192, 256, 0, stream>>>(h, ln2g + i * 256, ln2b + i * 256, abf);
        // FFN, 2 hidden chunks of 512
        for (int c = 0; c < 2; ++c) {
            gemm_bf16<1,0,1,1><<<dim3(256, 4, 1), 256, 0, stream>>>(abf, W1T_i + c * 131072,
                b1 + (long)i * 1024 + c * 512, (ushort*)qbuf,
                256, 256, 256, 512, 0, 0, 0);
            if (c == 0)
                gemm_bf16<0,1,0,1><<<dim3(256, 2, 1), 256, 0, stream>>>((ushort*)qbuf,
                    W2T_i + c * 512, b2 + i * 256, h, 512, 512, 1024, 256, 0, 0, 0);
            else
                gemm_bf16<0,1,0,0><<<dim3(256, 2, 1), 256, 0, stream>>>((ushort*)qbuf,
                    W2T_i + c * 512, nullptr, h, 512, 512, 1024, 256, 0, 0, 0);
        }
    }
    out_kernel<<<8192, 256, 0, stream>>>(h, Wout, bout, outp);
}

// Round 3
// 1137.315 us; speedup vs baseline: 5.1323x; 2.4768x over previous
//
#include <hip/hip_runtime.h>
#include <hip/hip_bf16.h>

// Model dims: B=16, N=2048, F=40, D=256, H=8, K=256, L=4, DH=32
// fp32 inputs/outputs; bf16 MFMA for all GEMMs and attention, fp32 residual stream.

typedef short bf16x8 __attribute__((ext_vector_type(8)));
typedef float f32x4 __attribute__((ext_vector_type(4)));

#define GLOBAL_AS __attribute__((address_space(1)))
#define LDS_AS __attribute__((address_space(3)))

static __device__ __forceinline__ float gelu_f(float v) {
    return 0.5f * v * (1.0f + erff(v * 0.70710678118654752f));
}
static __device__ __forceinline__ ushort f2bf(float x) {
    __hip_bfloat16 h = __float2bfloat16(x);
    return __builtin_bit_cast(ushort, h);
}

// ---------------- embed + pos + LN0 (one block per row), fp32 out ----------------
__global__ __launch_bounds__(256)
void embed_ln_kernel(const float* __restrict__ x, const float* __restrict__ Wemb,
                     const float* __restrict__ bemb, const float* __restrict__ pos,
                     const float* __restrict__ g0, const float* __restrict__ b0,
                     float* __restrict__ H)
{
    __shared__ float xs[40];
    __shared__ float red[4];
    const int row = blockIdx.x;
    const int n = row & 2047;
    const int d = threadIdx.x;
    if (d < 40) xs[d] = x[(long)row * 40 + d];
    __syncthreads();
    float v = bemb[d] + pos[(long)n * 256 + d];
    #pragma unroll 8
    for (int f = 0; f < 40; ++f) v += xs[f] * Wemb[f * 256 + d];
    float s = v;
    #pragma unroll
    for (int m = 32; m >= 1; m >>= 1) s += __shfl_xor(s, m);
    const int wid = d >> 6;
    if ((d & 63) == 0) red[wid] = s;
    __syncthreads();
    const float mean = (red[0] + red[1] + red[2] + red[3]) * (1.0f / 256.0f);
    const float dv = v - mean;
    float q = dv * dv;
    #pragma unroll
    for (int m = 32; m >= 1; m >>= 1) q += __shfl_xor(q, m);
    __syncthreads();
    if ((d & 63) == 0) red[wid] = q;
    __syncthreads();
    const float var = (red[0] + red[1] + red[2] + red[3]) * (1.0f / 256.0f);
    H[(long)row * 256 + d] = dv * rsqrtf(var + 1e-5f) * g0[d] + b0[d];
}

// ---------------- LayerNorm fp32 -> bf16 ----------------
__global__ __launch_bounds__(256)
void ln_kernel(const float* __restrict__ X, const float* __restrict__ g,
               const float* __restrict__ b, ushort* __restrict__ Y)
{
    const int row = blockIdx.x * 4 + (threadIdx.x >> 6);
    const int lane = threadIdx.x & 63;
    const long base = (long)row * 256 + lane * 4;
    float4 xv = *(const float4*)&X[base];
    float s = xv.x + xv.y + xv.z + xv.w;
    #pragma unroll
    for (int m = 32; m >= 1; m >>= 1) s += __shfl_xor(s, m);
    const float mean = s * (1.0f / 256.0f);
    const float dx = xv.x - mean, dy = xv.y - mean, dz = xv.z - mean, dw = xv.w - mean;
    float q = dx * dx + dy * dy + dz * dz + dw * dw;
    #pragma unroll
    for (int m = 32; m >= 1; m >>= 1) q += __shfl_xor(q, m);
    const float inv = rsqrtf(q * (1.0f / 256.0f) + 1e-5f);
    const float4 gv = *(const float4*)&g[lane * 4];
    const float4 bv = *(const float4*)&b[lane * 4];
    ushort4 y;
    y.x = f2bf(dx * inv * gv.x + bv.x);
    y.y = f2bf(dy * inv * gv.y + bv.y);
    y.z = f2bf(dz * inv * gv.z + bv.z);
    y.w = f2bf(dw * inv * gv.w + bv.w);
    *(ushort4*)&Y[base] = y;
}

// ---------------- weight transpose + cast ----------------
__global__ __launch_bounds__(256)
void transpose_cast(const float* __restrict__ in, ushort* __restrict__ out,
                    int R, int C, long sIn, long sOut)
{
    __shared__ float tile[32][33];
    in += (long)blockIdx.z * sIn; out += (long)blockIdx.z * sOut;
    const int c0 = blockIdx.x * 32, r0 = blockIdx.y * 32;
    const int tx = threadIdx.x & 31, ty = threadIdx.x >> 5;
    #pragma unroll
    for (int j = 0; j < 4; ++j)
        tile[ty + j * 8][tx] = in[(long)(r0 + ty + j * 8) * C + c0 + tx];
    __syncthreads();
    #pragma unroll
    for (int j = 0; j < 4; ++j)
        out[(long)(c0 + ty + j * 8) * R + r0 + tx] = f2bf(tile[tx][ty + j * 8]);
}

// ---------------- activation transpose: abf [32768,256] -> aT [16][256][2048] ----------------
__global__ __launch_bounds__(256)
void transpose_act(const ushort* __restrict__ in, ushort* __restrict__ out)
{
    __shared__ ushort tile[32][33];
    const int c0 = blockIdx.x * 32, r0 = blockIdx.y * 32;
    const int tx = threadIdx.x & 31, ty = threadIdx.x >> 5;
    #pragma unroll
    for (int j = 0; j < 4; ++j)
        tile[ty + j * 8][tx] = in[(long)(r0 + ty + j * 8) * 256 + c0 + tx];
    __syncthreads();
    const int b = r0 >> 11, nn = r0 & 2047;
    #pragma unroll
    for (int j = 0; j < 4; ++j)
        out[((long)(b * 256 + c0 + ty + j * 8)) * 2048 + nn + tx] = tile[tx][ty + j * 8];
}

// ---------------- bf16 MFMA GEMM, m97 structure ----------------
template<int OBF16, int ACCUM, int ACT, int HASB>
__global__ __launch_bounds__(256)
void gemm_bf16(const ushort* __restrict__ A, const ushort* __restrict__ BT,
               const float* __restrict__ bias, void* __restrict__ Cout,
               int Kd, int lda, int ldb, int ldc,
               long sA, long sBT, long sC)
{
    __shared__ ushort Als[128 * 32];
    __shared__ ushort Bls[128 * 32];
    const int bz = blockIdx.z;
    const ushort* Ab = A + (long)bz * sA;
    const ushort* Bb = BT + (long)bz * sBT;
    const int m0 = blockIdx.x * 128, n0 = blockIdx.y * 128;
    const int t = threadIdx.x, l = t & 63, w = t >> 6;
    const int wr = w >> 1, wc = w & 1;
    const int fr = l & 15, fq = l >> 4;

    f32x4 acc[4][4];
    #pragma unroll
    for (int m = 0; m < 4; ++m)
        #pragma unroll
        for (int n = 0; n < 4; ++n) acc[m][n] = f32x4{0.f, 0.f, 0.f, 0.f};

    const int srow = t >> 2;
    const int skcol = (t & 3) * 8;
    const int dst0 = w * 512;

    for (int kk = 0; kk < Kd; kk += 32) {
        const ushort* ag = Ab + (long)(m0 + srow) * lda + kk + skcol;
        const ushort* bg = Bb + (long)(n0 + srow) * ldb + kk + skcol;
        __builtin_amdgcn_global_load_lds((const GLOBAL_AS void*)ag,
                                         (LDS_AS void*)&Als[dst0], 16, 0, 0);
        __builtin_amdgcn_global_load_lds((const GLOBAL_AS void*)(ag + (long)64 * lda),
                                         (LDS_AS void*)&Als[2048 + dst0], 16, 0, 0);
        __builtin_amdgcn_global_load_lds((const GLOBAL_AS void*)bg,
                                         (LDS_AS void*)&Bls[dst0], 16, 0, 0);
        __builtin_amdgcn_global_load_lds((const GLOBAL_AS void*)(bg + (long)64 * ldb),
                                         (LDS_AS void*)&Bls[2048 + dst0], 16, 0, 0);
        __syncthreads();
        bf16x8 af[4], bfv[4];
        #pragma unroll
        for (int m = 0; m < 4; ++m)
            af[m] = *(const bf16x8*)&Als[(wr * 64 + m * 16 + fr) * 32 + fq * 8];
        #pragma unroll
        for (int n = 0; n < 4; ++n)
            bfv[n] = *(const bf16x8*)&Bls[(wc * 64 + n * 16 + fr) * 32 + fq * 8];
        #pragma unroll
        for (int m = 0; m < 4; ++m)
            #pragma unroll
            for (int n = 0; n < 4; ++n)
                acc[m][n] = __builtin_amdgcn_mfma_f32_16x16x32_bf16(af[m], bfv[n], acc[m][n], 0, 0, 0);
        __syncthreads();
    }

    float bsv[4] = {0.f, 0.f, 0.f, 0.f};
    if (HASB) {
        #pragma unroll
        for (int n = 0; n < 4; ++n) bsv[n] = bias[n0 + wc * 64 + n * 16 + fr];
    }
    #pragma unroll
    for (int m = 0; m < 4; ++m) {
        #pragma unroll
        for (int r = 0; r < 4; ++r) {
            const int grow = m0 + wr * 64 + m * 16 + fq * 4 + r;
            const long rowoff = (long)grow * ldc + n0 + wc * 64 + fr;
            #pragma unroll
            for (int n = 0; n < 4; ++n) {
                float v = acc[m][n][r] + bsv[n];
                if (ACT) v = gelu_f(v);
                const long off = rowoff + n * 16;
                if (OBF16) {
                    ((ushort*)Cout)[(long)bz * sC + off] = f2bf(v);
                } else {
                    float* Cp = (float*)Cout + (long)bz * sC;
                    if (ACCUM) v += Cp[off];
                    Cp[off] = v;
                }
            }
        }
    }
}

// ---------------- fused MFMA attention ----------------
// grid (N/64, H, B), 256 threads (4 waves, each 16 q-rows).
// Q: [B*N,256] bf16 (head slice h*32), Kp: [B][256][256] bf16 (row=key, col=h*32+d),
// VpT: [B][256][256] bf16 (row=h*32+d, col=key), O: [B*N,256] bf16.
__global__ __launch_bounds__(256)
void attn_mfma(const ushort* __restrict__ Q, const ushort* __restrict__ Kp,
               const ushort* __restrict__ VpT, ushort* __restrict__ O)
{
    __shared__ ushort Qls[64 * 40];    // rows 64, stride 40 (pad 8)
    __shared__ ushort Kls[256 * 40];   // rows 256 keys
    __shared__ ushort Vls[32 * 264];   // rows 32 d, cols 256 keys (pad 8)
    __shared__ ushort Pls[64 * 264];   // rows 64 q, cols 256 keys (pad 8)
    const int qt = blockIdx.x, h = blockIdx.y, b = blockIdx.z;
    const int n0 = qt * 64;
    const int t = threadIdx.x, w = t >> 6, l = t & 63;
    const int fr = l & 15, fq = l >> 4;

    // stage Q (64 rows x 32 d)
    {
        const int r = t >> 2, c = (t & 3) * 8;
        *(float4*)&Qls[r * 40 + c] =
            *(const float4*)&Q[((long)(b * 2048 + n0 + r)) * 256 + h * 32 + c];
    }
    // stage K (256 rows x 32 d)
    #pragma unroll
    for (int it = 0; it < 4; ++it) {
        const int r = (t >> 2) + it * 64, c = (t & 3) * 8;
        *(float4*)&Kls[r * 40 + c] =
            *(const float4*)&Kp[((long)(b * 256 + r)) * 256 + h * 32 + c];
    }
    // stage Vt (32 rows d x 256 keys)
    {
        const int r = t >> 3, c0 = (t & 7) * 32;
        const ushort* src = VpT + ((long)(b * 256 + h * 32 + r)) * 256 + c0;
        #pragma unroll
        for (int j = 0; j < 4; ++j)
            *(float4*)&Vls[r * 264 + c0 + j * 8] = *(const float4*)(src + j * 8);
    }
    __syncthreads();

    // S = Q @ K^T for rows w*16..w*16+15 (one A-frag, 16 B-frags)
    const bf16x8 aq = *(const bf16x8*)&Qls[(w * 16 + fr) * 40 + fq * 8];
    f32x4 s[16];
    #pragma unroll
    for (int n = 0; n < 16; ++n) {
        const bf16x8 bk = *(const bf16x8*)&Kls[(n * 16 + fr) * 40 + fq * 8];
        s[n] = __builtin_amdgcn_mfma_f32_16x16x32_bf16(aq, bk, f32x4{0.f,0.f,0.f,0.f}, 0, 0, 0);
    }
    // softmax: lane holds rows fq*4+r (within strip), col n*16+fr
    const float scale = 0.17677669529663687f;   // 1/sqrt(32)
    float mx[4] = {-1e30f, -1e30f, -1e30f, -1e30f};
    #pragma unroll
    for (int n = 0; n < 16; ++n)
        #pragma unroll
        for (int r = 0; r < 4; ++r) { s[n][r] *= scale; mx[r] = fmaxf(mx[r], s[n][r]); }
    #pragma unroll
    for (int m = 1; m <= 8; m <<= 1)
        #pragma unroll
        for (int r = 0; r < 4; ++r) mx[r] = fmaxf(mx[r], __shfl_xor(mx[r], m));
    float sm[4] = {0.f, 0.f, 0.f, 0.f};
    #pragma unroll
    for (int n = 0; n < 16; ++n)
        #pragma unroll
        for (int r = 0; r < 4; ++r) {
            const float e = __expf(s[n][r] - mx[r]);
            s[n][r] = e; sm[r] += e;
        }
    #pragma unroll
    for (int m = 1; m <= 8; m <<= 1)
        #pragma unroll
        for (int r = 0; r < 4; ++r) sm[r] += __shfl_xor(sm[r], m);
    // write P to LDS (rows w*16+fq*4+r, col n*16+fr)
    #pragma unroll
    for (int n = 0; n < 16; ++n)
        #pragma unroll
        for (int r = 0; r < 4; ++r)
            Pls[(w * 16 + fq * 4 + r) * 264 + n * 16 + fr] = f2bf(s[n][r]);
    __syncthreads();

    // O = P @ V : 8 k-steps, 2 d-frags
    f32x4 o[2] = {f32x4{0.f,0.f,0.f,0.f}, f32x4{0.f,0.f,0.f,0.f}};
    #pragma unroll
    for (int kk = 0; kk < 8; ++kk) {
        const bf16x8 ap = *(const bf16x8*)&Pls[(w * 16 + fr) * 264 + kk * 32 + fq * 8];
        #pragma unroll
        for (int n = 0; n < 2; ++n) {
            const bf16x8 bv = *(const bf16x8*)&Vls[(n * 16 + fr) * 264 + kk * 32 + fq * 8];
            o[n] = __builtin_amdgcn_mfma_f32_16x16x32_bf16(ap, bv, o[n], 0, 0, 0);
        }
    }
    // epilogue: rows w*16+fq*4+r, col h*32+n*16+fr, normalized
    float inv[4];
    #pragma unroll
    for (int r = 0; r < 4; ++r) inv[r] = 1.0f / sm[r];
    #pragma unroll
    for (int n = 0; n < 2; ++n)
        #pragma unroll
        for (int r = 0; r < 4; ++r)
            O[((long)(b * 2048 + n0 + w * 16 + fq * 4 + r)) * 256 + h * 32 + n * 16 + fr] =
                f2bf(o[n][r] * inv[r]);
}

// ---------------- final head ----------------
__global__ __launch_bounds__(256)
void out_kernel(const float* __restrict__ H, const float* __restrict__ Wout,
                const float* __restrict__ bout, float* __restrict__ out)
{
    const int row = blockIdx.x * 4 + (threadIdx.x >> 6);
    const int lane = threadIdx.x & 63;
    float4 hv = *(const float4*)&H[(long)row * 256 + lane * 4];
    float4 wv = *(const float4*)&Wout[lane * 4];
    float s = hv.x * wv.x + hv.y * wv.y + hv.z * wv.z + hv.w * wv.w;
    #pragma unroll
    for (int m = 32; m >= 1; m >>= 1) s += __shfl_xor(s, m);
    if (lane == 0) out[row] = s + bout[0];
}

extern "C" void kernel_launch(void* const* d_in, const int* in_sizes, int n_in,
                              void* d_out, int out_size, void* d_ws, size_t ws_size,
                              hipStream_t stream)
{
    const float* x    = (const float*)d_in[0];
    const float* Wemb = (const float*)d_in[1];
    const float* bemb = (const float*)d_in[2];
    const float* pos  = (const float*)d_in[3];
    const float* ln0g = (const float*)d_in[4];
    const float* ln0b = (const float*)d_in[5];
    const float* ln1g = (const float*)d_in[6];
    const float* ln1b = (const float*)d_in[7];
    const float* Wq   = (const float*)d_in[8];
    const float* Wk   = (const float*)d_in[9];
    const float* Wv   = (const float*)d_in[10];
    const float* Ek   = (const float*)d_in[11];
    const float* Ev   = (const float*)d_in[12];
    const float* Wo   = (const float*)d_in[13];
    const float* bo   = (const float*)d_in[14];
    const float* ln2g = (const float*)d_in[15];
    const float* ln2b = (const float*)d_in[16];
    const float* W1   = (const float*)d_in[17];
    const float* b1   = (const float*)d_in[18];
    const float* W2   = (const float*)d_in[19];
    const float* b2   = (const float*)d_in[20];
    const float* Wout = (const float*)d_in[21];
    const float* bout = (const float*)d_in[22];

    char* ws = (char*)d_ws;
    float*  h    = (float*)(ws + 0);                    // 33.5 MB
    ushort* abf  = (ushort*)(ws + 33554432L);           // 16.8 MB  [32768,256] bf16
    ushort* aT   = (ushort*)(ws + 50331648L);           // 16.8 MB  [16][256][2048] bf16
    ushort* qbf  = (ushort*)(ws + 67108864L);           // 33.5 MB  q bf16 / FFN hidden bf16 [32768,512]
    ushort* apkv = (ushort*)(ws + 100663296L);          //  4.2 MB  [16][512][256] bf16
    ushort* kp   = (ushort*)(ws + 104857600L);          //  2.1 MB  [16][256][256] bf16 (row=key)
    ushort* vpT  = (ushort*)(ws + 109051904L);          //  2.1 MB  [16][256][256] bf16 (row=d)
    ushort* WT   = (ushort*)(ws + 113246208L);          // 14.7 MB
    ushort* WqT  = WT;
    ushort* WkT  = WT + 262144;
    ushort* WvT  = WT + 524288;
    ushort* WoT  = WT + 786432;
    ushort* W1T  = WT + 1048576;
    ushort* W2T  = WT + 2097152;
    ushort* EkvT = WT + 3145728;
    float* outp = (float*)d_out;

    transpose_cast<<<dim3(8, 8, 4), 256, 0, stream>>>(Wq, WqT, 256, 256, 65536, 65536);
    transpose_cast<<<dim3(8, 8, 4), 256, 0, stream>>>(Wk, WkT, 256, 256, 65536, 65536);
    transpose_cast<<<dim3(8, 8, 4), 256, 0, stream>>>(Wv, WvT, 256, 256, 65536, 65536);
    transpose_cast<<<dim3(8, 8, 4), 256, 0, stream>>>(Wo, WoT, 256, 256, 65536, 65536);
    transpose_cast<<<dim3(32, 8, 4), 256, 0, stream>>>(W1, W1T, 256, 1024, 262144, 262144);
    transpose_cast<<<dim3(8, 32, 4), 256, 0, stream>>>(W2, W2T, 1024, 256, 262144, 262144);
    transpose_cast<<<dim3(8, 64, 4), 256, 0, stream>>>(Ek, EkvT, 2048, 256, 524288, 1048576);
    transpose_cast<<<dim3(8, 64, 4), 256, 0, stream>>>(Ev, EkvT + 524288, 2048, 256, 524288, 1048576);

    embed_ln_kernel<<<32768, 256, 0, stream>>>(x, Wemb, bemb, pos, ln0g, ln0b, h);

    for (int i = 0; i < 4; ++i) {
        const ushort* WqT_i = WqT + i * 65536;
        const ushort* WkT_i = WkT + i * 65536;
        const ushort* WvT_i = WvT + i * 65536;
        const ushort* WoT_i = WoT + i * 65536;
        const ushort* W1T_i = W1T + i * 262144;
        const ushort* W2T_i = W2T + i * 262144;
        const ushort* EkvT_i = EkvT + (long)i * 1048576;

        // a = LN1(h) -> bf16 ; aT = transpose(a)
        ln_kernel<<<8192, 256, 0, stream>>>(h, ln1g + i * 256, ln1b + i * 256, abf);
        transpose_act<<<dim3(8, 1024), 256, 0, stream>>>(abf, aT);
        // q = a @ Wq  (bf16 out)
        gemm_bf16<1,0,0,0><<<dim3(256, 2, 1), 256, 0, stream>>>(abf, WqT_i, nullptr, qbf,
            256, 256, 256, 256, 0, 0, 0);
        // apkv[b] = [Ek^T; Ev^T] @ a[b]  (bf16 out)
        gemm_bf16<1,0,0,0><<<dim3(4, 2, 16), 256, 0, stream>>>(EkvT_i, aT, nullptr, apkv,
            2048, 2048, 2048, 256, 0, 524288, 131072);
        // kp[b] = apk[b] @ Wk (bf16, row=key)
        gemm_bf16<1,0,0,0><<<dim3(2, 2, 16), 256, 0, stream>>>(apkv, WkT_i, nullptr, kp,
            256, 256, 256, 256, 131072, 0, 65536);
        // vpT[b] = Wv^T @ apv[b]^T  (bf16, row=d, col=key)
        gemm_bf16<1,0,0,0><<<dim3(2, 2, 16), 256, 0, stream>>>(WvT_i, apkv + 65536, nullptr, vpT,
            256, 256, 256, 256, 0, 131072, 65536);
        // fused MFMA attention -> abf (bf16)
        attn_mfma<<<dim3(32, 8, 16), 256, 0, stream>>>(qbf, kp, vpT, abf);
        // h += attnout @ Wo + bo
        gemm_bf16<0,1,0,1><<<dim3(256, 2, 1), 256, 0, stream>>>(abf, WoT_i, bo + i * 256, h,
            256, 256, 256, 256, 0, 0, 0);
        // a = LN2(h)
        ln_kernel<<<8192, 256, 0, stream>>>(h, ln2g + i * 256, ln2b + i * 256, abf);
        // FFN, 2 hidden chunks of 512
        for (int c = 0; c < 2; ++c) {
            gemm_bf16<1,0,1,1><<<dim3(256, 4, 1), 256, 0, stream>>>(abf, W1T_i + c * 131072,
                b1 + (long)i * 1024 + c * 512, qbf,
                256, 256, 256, 512, 0, 0, 0);
            if (c == 0)
                gemm_bf16<0,1,0,1><<<dim3(256, 2, 1), 256, 0, stream>>>(qbf,
                    W2T_i + c * 512, b2 + i * 256, h, 512, 512, 1024, 256, 0, 0, 0);
            else
                gemm_bf16<0,1,0,0><<<dim3(256, 2, 1), 256, 0, stream>>>(qbf,
                    W2T_i + c * 512, nullptr, h, 512, 512, 1024, 256, 0, 0, 0);
        }
    }
    out_kernel<<<8192, 256, 0, stream>>>(h, Wout, bout, outp);
}

// Round 4
// 1014.084 us; speedup vs baseline: 5.7560x; 1.1215x over previous
//
#include <hip/hip_runtime.h>
#include <hip/hip_bf16.h>

// Model dims: B=16, N=2048, F=40, D=256, H=8, K=256, L=4, DH=32
// fp32 inputs/outputs; bf16 MFMA for all GEMMs and attention, fp32 residual stream.

typedef short bf16x8 __attribute__((ext_vector_type(8)));
typedef float f32x4 __attribute__((ext_vector_type(4)));

#define GLOBAL_AS __attribute__((address_space(1)))
#define LDS_AS __attribute__((address_space(3)))

static __device__ __forceinline__ float gelu_f(float v) {
    return 0.5f * v * (1.0f + erff(v * 0.70710678118654752f));
}
static __device__ __forceinline__ ushort f2bf(float x) {
    __hip_bfloat16 h = __float2bfloat16(x);
    return __builtin_bit_cast(ushort, h);
}

// ---------------- embed + pos + LN0: wave-per-row, no syncthreads ----------------
__global__ __launch_bounds__(256)
void embed_ln2(const float* __restrict__ x, const float* __restrict__ Wemb,
               const float* __restrict__ bemb, const float* __restrict__ pos,
               const float* __restrict__ g0, const float* __restrict__ b0,
               float* __restrict__ H)
{
    const int t = threadIdx.x, w = t >> 6, l = t & 63;
    const long row = (long)blockIdx.x * 4 + w;
    const int n = (int)(row & 2047);
    const float xl = (l < 40) ? x[row * 40 + l] : 0.f;
    float4 acc = *(const float4*)&bemb[l * 4];
    const float4 pv = *(const float4*)&pos[(long)n * 256 + l * 4];
    acc.x += pv.x; acc.y += pv.y; acc.z += pv.z; acc.w += pv.w;
    #pragma unroll 8
    for (int f = 0; f < 40; ++f) {
        const float xf = __shfl(xl, f);
        const float4 wv = *(const float4*)&Wemb[f * 256 + l * 4];
        acc.x += xf * wv.x; acc.y += xf * wv.y; acc.z += xf * wv.z; acc.w += xf * wv.w;
    }
    float s = acc.x + acc.y + acc.z + acc.w;
    #pragma unroll
    for (int m = 32; m >= 1; m >>= 1) s += __shfl_xor(s, m);
    const float mean = s * (1.0f / 256.0f);
    const float dx = acc.x - mean, dy = acc.y - mean, dz = acc.z - mean, dw = acc.w - mean;
    float q = dx * dx + dy * dy + dz * dz + dw * dw;
    #pragma unroll
    for (int m = 32; m >= 1; m >>= 1) q += __shfl_xor(q, m);
    const float inv = rsqrtf(q * (1.0f / 256.0f) + 1e-5f);
    const float4 gv = *(const float4*)&g0[l * 4];
    const float4 bv = *(const float4*)&b0[l * 4];
    float4 y;
    y.x = dx * inv * gv.x + bv.x;
    y.y = dy * inv * gv.y + bv.y;
    y.z = dz * inv * gv.z + bv.z;
    y.w = dw * inv * gv.w + bv.w;
    *(float4*)&H[row * 256 + l * 4] = y;
}

// ---------------- LayerNorm fp32 -> bf16 ----------------
__global__ __launch_bounds__(256)
void ln_kernel(const float* __restrict__ X, const float* __restrict__ g,
               const float* __restrict__ b, ushort* __restrict__ Y)
{
    const int row = blockIdx.x * 4 + (threadIdx.x >> 6);
    const int lane = threadIdx.x & 63;
    const long base = (long)row * 256 + lane * 4;
    float4 xv = *(const float4*)&X[base];
    float s = xv.x + xv.y + xv.z + xv.w;
    #pragma unroll
    for (int m = 32; m >= 1; m >>= 1) s += __shfl_xor(s, m);
    const float mean = s * (1.0f / 256.0f);
    const float dx = xv.x - mean, dy = xv.y - mean, dz = xv.z - mean, dw = xv.w - mean;
    float q = dx * dx + dy * dy + dz * dz + dw * dw;
    #pragma unroll
    for (int m = 32; m >= 1; m >>= 1) q += __shfl_xor(q, m);
    const float inv = rsqrtf(q * (1.0f / 256.0f) + 1e-5f);
    const float4 gv = *(const float4*)&g[lane * 4];
    const float4 bv = *(const float4*)&b[lane * 4];
    ushort4 y;
    y.x = f2bf(dx * inv * gv.x + bv.x);
    y.y = f2bf(dy * inv * gv.y + bv.y);
    y.z = f2bf(dz * inv * gv.z + bv.z);
    y.w = f2bf(dw * inv * gv.w + bv.w);
    *(ushort4*)&Y[base] = y;
}

// ---------------- weight transpose + cast ----------------
__global__ __launch_bounds__(256)
void transpose_cast(const float* __restrict__ in, ushort* __restrict__ out,
                    int R, int C, long sIn, long sOut)
{
    __shared__ float tile[32][33];
    in += (long)blockIdx.z * sIn; out += (long)blockIdx.z * sOut;
    const int c0 = blockIdx.x * 32, r0 = blockIdx.y * 32;
    const int tx = threadIdx.x & 31, ty = threadIdx.x >> 5;
    #pragma unroll
    for (int j = 0; j < 4; ++j)
        tile[ty + j * 8][tx] = in[(long)(r0 + ty + j * 8) * C + c0 + tx];
    __syncthreads();
    #pragma unroll
    for (int j = 0; j < 4; ++j)
        out[(long)(c0 + ty + j * 8) * R + r0 + tx] = f2bf(tile[tx][ty + j * 8]);
}

// ---------------- activation transpose: abf [32768,256] -> aT [16][256][2048] ----------------
__global__ __launch_bounds__(256)
void transpose_act(const ushort* __restrict__ in, ushort* __restrict__ out)
{
    __shared__ ushort tile[32][33];
    const int c0 = blockIdx.x * 32, r0 = blockIdx.y * 32;
    const int tx = threadIdx.x & 31, ty = threadIdx.x >> 5;
    #pragma unroll
    for (int j = 0; j < 4; ++j)
        tile[ty + j * 8][tx] = in[(long)(r0 + ty + j * 8) * 256 + c0 + tx];
    __syncthreads();
    const int b = r0 >> 11, nn = r0 & 2047;
    #pragma unroll
    for (int j = 0; j < 4; ++j)
        out[((long)(b * 256 + c0 + ty + j * 8)) * 2048 + nn + tx] = tile[tx][ty + j * 8];
}

// ---------------- bf16 MFMA GEMM, m97 structure ----------------
template<int OBF16, int ACCUM, int ACT, int HASB>
__global__ __launch_bounds__(256)
void gemm_bf16(const ushort* __restrict__ A, const ushort* __restrict__ BT,
               const float* __restrict__ bias, void* __restrict__ Cout,
               int Kd, int lda, int ldb, int ldc,
               long sA, long sBT, long sC)
{
    __shared__ ushort Als[128 * 32];
    __shared__ ushort Bls[128 * 32];
    const int bz = blockIdx.z;
    const ushort* Ab = A + (long)bz * sA;
    const ushort* Bb = BT + (long)bz * sBT;
    const int m0 = blockIdx.x * 128, n0 = blockIdx.y * 128;
    const int t = threadIdx.x, l = t & 63, w = t >> 6;
    const int wr = w >> 1, wc = w & 1;
    const int fr = l & 15, fq = l >> 4;

    f32x4 acc[4][4];
    #pragma unroll
    for (int m = 0; m < 4; ++m)
        #pragma unroll
        for (int n = 0; n < 4; ++n) acc[m][n] = f32x4{0.f, 0.f, 0.f, 0.f};

    const int srow = t >> 2;
    const int skcol = (t & 3) * 8;
    const int dst0 = w * 512;

    for (int kk = 0; kk < Kd; kk += 32) {
        const ushort* ag = Ab + (long)(m0 + srow) * lda + kk + skcol;
        const ushort* bg = Bb + (long)(n0 + srow) * ldb + kk + skcol;
        __builtin_amdgcn_global_load_lds((const GLOBAL_AS void*)ag,
                                         (LDS_AS void*)&Als[dst0], 16, 0, 0);
        __builtin_amdgcn_global_load_lds((const GLOBAL_AS void*)(ag + (long)64 * lda),
                                         (LDS_AS void*)&Als[2048 + dst0], 16, 0, 0);
        __builtin_amdgcn_global_load_lds((const GLOBAL_AS void*)bg,
                                         (LDS_AS void*)&Bls[dst0], 16, 0, 0);
        __builtin_amdgcn_global_load_lds((const GLOBAL_AS void*)(bg + (long)64 * ldb),
                                         (LDS_AS void*)&Bls[2048 + dst0], 16, 0, 0);
        __syncthreads();
        bf16x8 af[4], bfv[4];
        #pragma unroll
        for (int m = 0; m < 4; ++m)
            af[m] = *(const bf16x8*)&Als[(wr * 64 + m * 16 + fr) * 32 + fq * 8];
        #pragma unroll
        for (int n = 0; n < 4; ++n)
            bfv[n] = *(const bf16x8*)&Bls[(wc * 64 + n * 16 + fr) * 32 + fq * 8];
        #pragma unroll
        for (int m = 0; m < 4; ++m)
            #pragma unroll
            for (int n = 0; n < 4; ++n)
                acc[m][n] = __builtin_amdgcn_mfma_f32_16x16x32_bf16(af[m], bfv[n], acc[m][n], 0, 0, 0);
        __syncthreads();
    }

    float bsv[4] = {0.f, 0.f, 0.f, 0.f};
    if (HASB) {
        #pragma unroll
        for (int n = 0; n < 4; ++n) bsv[n] = bias[n0 + wc * 64 + n * 16 + fr];
    }
    #pragma unroll
    for (int m = 0; m < 4; ++m) {
        #pragma unroll
        for (int r = 0; r < 4; ++r) {
            const int grow = m0 + wr * 64 + m * 16 + fq * 4 + r;
            const long rowoff = (long)grow * ldc + n0 + wc * 64 + fr;
            #pragma unroll
            for (int n = 0; n < 4; ++n) {
                float v = acc[m][n][r] + bsv[n];
                if (ACT) v = gelu_f(v);
                const long off = rowoff + n * 16;
                if (OBF16) {
                    ((ushort*)Cout)[(long)bz * sC + off] = f2bf(v);
                } else {
                    float* Cp = (float*)Cout + (long)bz * sC;
                    if (ACCUM) v += Cp[off];
                    Cp[off] = v;
                }
            }
        }
    }
}

// ---------------- fused LN2 + FFN: h += gelu(LN2(h)@W1+b1)@W2 + b2 ----------------
// grid 512 (64-row strips), 256 threads (4 waves).
// W1T: [1024][256] bf16 (row=hidden col), W2T: [256][1024] bf16 (row=out col).
__global__ __launch_bounds__(256)
void ffn_fused(float* __restrict__ Hbuf, const float* __restrict__ g,
               const float* __restrict__ b, const ushort* __restrict__ W1T,
               const float* __restrict__ b1, const ushort* __restrict__ W2T,
               const float* __restrict__ b2)
{
    __shared__ ushort a_tile[64 * 264];   // LN2 output, rows 64, stride 264 (33*8: b128-conflict-free)
    __shared__ ushort hid[64 * 136];      // hidden chunk, stride 136 (17*8)
    const int t = threadIdx.x, w = t >> 6, l = t & 63;
    const int fr = l & 15, fq = l >> 4;
    const long row0 = (long)blockIdx.x * 64;

    // LN2: wave w handles rows w*16 .. w*16+15; lane covers 4 cols
    {
        const float4 gv = *(const float4*)&g[l * 4];
        const float4 bv = *(const float4*)&b[l * 4];
        for (int rr = 0; rr < 16; ++rr) {
            const int r = w * 16 + rr;
            float4 xv = *(const float4*)&Hbuf[(row0 + r) * 256 + l * 4];
            float s = xv.x + xv.y + xv.z + xv.w;
            #pragma unroll
            for (int m = 32; m >= 1; m >>= 1) s += __shfl_xor(s, m);
            const float mean = s * (1.0f / 256.0f);
            const float dx = xv.x - mean, dy = xv.y - mean, dz = xv.z - mean, dw = xv.w - mean;
            float q = dx * dx + dy * dy + dz * dz + dw * dw;
            #pragma unroll
            for (int m = 32; m >= 1; m >>= 1) q += __shfl_xor(q, m);
            const float inv = rsqrtf(q * (1.0f / 256.0f) + 1e-5f);
            ushort4 y;
            y.x = f2bf(dx * inv * gv.x + bv.x);
            y.y = f2bf(dy * inv * gv.y + bv.y);
            y.z = f2bf(dz * inv * gv.z + bv.z);
            y.w = f2bf(dw * inv * gv.w + bv.w);
            *(ushort4*)&a_tile[r * 264 + l * 4] = y;
        }
    }
    __syncthreads();

    f32x4 acc_o[4][4];
    #pragma unroll
    for (int m = 0; m < 4; ++m)
        #pragma unroll
        for (int n = 0; n < 4; ++n) acc_o[m][n] = f32x4{0.f, 0.f, 0.f, 0.f};

    for (int hc = 0; hc < 8; ++hc) {
        // stage 1: hid[:, w*32 .. w*32+32) = gelu(a_tile @ W1c + b1c)
        f32x4 acc1[4][2];
        #pragma unroll
        for (int m = 0; m < 4; ++m)
            #pragma unroll
            for (int n = 0; n < 2; ++n) acc1[m][n] = f32x4{0.f, 0.f, 0.f, 0.f};
        const ushort* w1base = W1T + ((long)(hc * 128 + w * 32 + fr)) * 256 + fq * 8;
        #pragma unroll
        for (int kk = 0; kk < 8; ++kk) {
            bf16x8 afr[4];
            #pragma unroll
            for (int m = 0; m < 4; ++m)
                afr[m] = *(const bf16x8*)&a_tile[(m * 16 + fr) * 264 + kk * 32 + fq * 8];
            #pragma unroll
            for (int n = 0; n < 2; ++n) {
                const bf16x8 bw = *(const bf16x8*)(w1base + n * 16 * 256 + kk * 32);
                #pragma unroll
                for (int m = 0; m < 4; ++m)
                    acc1[m][n] = __builtin_amdgcn_mfma_f32_16x16x32_bf16(afr[m], bw, acc1[m][n], 0, 0, 0);
            }
        }
        float b1v[2];
        #pragma unroll
        for (int n = 0; n < 2; ++n) b1v[n] = b1[hc * 128 + w * 32 + n * 16 + fr];
        #pragma unroll
        for (int m = 0; m < 4; ++m)
            #pragma unroll
            for (int n = 0; n < 2; ++n)
                #pragma unroll
                for (int j = 0; j < 4; ++j)
                    hid[(m * 16 + fq * 4 + j) * 136 + w * 32 + n * 16 + fr] =
                        f2bf(gelu_f(acc1[m][n][j] + b1v[n]));
        __syncthreads();
        // stage 2: acc_o[:, w*64 .. w*64+64) += hid @ W2c
        const ushort* w2base = W2T + ((long)(w * 64 + fr)) * 1024 + hc * 128 + fq * 8;
        #pragma unroll
        for (int kk = 0; kk < 4; ++kk) {
            bf16x8 pfr[4];
            #pragma unroll
            for (int m = 0; m < 4; ++m)
                pfr[m] = *(const bf16x8*)&hid[(m * 16 + fr) * 136 + kk * 32 + fq * 8];
            #pragma unroll
            for (int n = 0; n < 4; ++n) {
                const bf16x8 bw = *(const bf16x8*)(w2base + (long)n * 16 * 1024 + kk * 32);
                #pragma unroll
                for (int m = 0; m < 4; ++m)
                    acc_o[m][n] = __builtin_amdgcn_mfma_f32_16x16x32_bf16(pfr[m], bw, acc_o[m][n], 0, 0, 0);
            }
        }
        __syncthreads();
    }

    float b2v[4];
    #pragma unroll
    for (int n = 0; n < 4; ++n) b2v[n] = b2[w * 64 + n * 16 + fr];
    #pragma unroll
    for (int m = 0; m < 4; ++m)
        #pragma unroll
        for (int j = 0; j < 4; ++j) {
            const long off = (row0 + m * 16 + fq * 4 + j) * 256 + w * 64 + fr;
            #pragma unroll
            for (int n = 0; n < 4; ++n)
                Hbuf[off + n * 16] += acc_o[m][n][j] + b2v[n];
        }
}

// ---------------- fused MFMA attention ----------------
__global__ __launch_bounds__(256)
void attn_mfma(const ushort* __restrict__ Q, const ushort* __restrict__ Kp,
               const ushort* __restrict__ VpT, ushort* __restrict__ O)
{
    __shared__ ushort Qls[64 * 40];
    __shared__ ushort Kls[256 * 40];
    __shared__ ushort Vls[32 * 264];
    __shared__ ushort Pls[64 * 264];
    const int qt = blockIdx.x, h = blockIdx.y, b = blockIdx.z;
    const int n0 = qt * 64;
    const int t = threadIdx.x, w = t >> 6, l = t & 63;
    const int fr = l & 15, fq = l >> 4;

    {
        const int r = t >> 2, c = (t & 3) * 8;
        *(float4*)&Qls[r * 40 + c] =
            *(const float4*)&Q[((long)(b * 2048 + n0 + r)) * 256 + h * 32 + c];
    }
    #pragma unroll
    for (int it = 0; it < 4; ++it) {
        const int r = (t >> 2) + it * 64, c = (t & 3) * 8;
        *(float4*)&Kls[r * 40 + c] =
            *(const float4*)&Kp[((long)(b * 256 + r)) * 256 + h * 32 + c];
    }
    {
        const int r = t >> 3, c0 = (t & 7) * 32;
        const ushort* src = VpT + ((long)(b * 256 + h * 32 + r)) * 256 + c0;
        #pragma unroll
        for (int j = 0; j < 4; ++j)
            *(float4*)&Vls[r * 264 + c0 + j * 8] = *(const float4*)(src + j * 8);
    }
    __syncthreads();

    const bf16x8 aq = *(const bf16x8*)&Qls[(w * 16 + fr) * 40 + fq * 8];
    f32x4 s[16];
    #pragma unroll
    for (int n = 0; n < 16; ++n) {
        const bf16x8 bk = *(const bf16x8*)&Kls[(n * 16 + fr) * 40 + fq * 8];
        s[n] = __builtin_amdgcn_mfma_f32_16x16x32_bf16(aq, bk, f32x4{0.f,0.f,0.f,0.f}, 0, 0, 0);
    }
    const float scale = 0.17677669529663687f;
    float mx[4] = {-1e30f, -1e30f, -1e30f, -1e30f};
    #pragma unroll
    for (int n = 0; n < 16; ++n)
        #pragma unroll
        for (int r = 0; r < 4; ++r) { s[n][r] *= scale; mx[r] = fmaxf(mx[r], s[n][r]); }
    #pragma unroll
    for (int m = 1; m <= 8; m <<= 1)
        #pragma unroll
        for (int r = 0; r < 4; ++r) mx[r] = fmaxf(mx[r], __shfl_xor(mx[r], m));
    float sm[4] = {0.f, 0.f, 0.f, 0.f};
    #pragma unroll
    for (int n = 0; n < 16; ++n)
        #pragma unroll
        for (int r = 0; r < 4; ++r) {
            const float e = __expf(s[n][r] - mx[r]);
            s[n][r] = e; sm[r] += e;
        }
    #pragma unroll
    for (int m = 1; m <= 8; m <<= 1)
        #pragma unroll
        for (int r = 0; r < 4; ++r) sm[r] += __shfl_xor(sm[r], m);
    #pragma unroll
    for (int n = 0; n < 16; ++n)
        #pragma unroll
        for (int r = 0; r < 4; ++r)
            Pls[(w * 16 + fq * 4 + r) * 264 + n * 16 + fr] = f2bf(s[n][r]);
    __syncthreads();

    f32x4 o[2] = {f32x4{0.f,0.f,0.f,0.f}, f32x4{0.f,0.f,0.f,0.f}};
    #pragma unroll
    for (int kk = 0; kk < 8; ++kk) {
        const bf16x8 ap = *(const bf16x8*)&Pls[(w * 16 + fr) * 264 + kk * 32 + fq * 8];
        #pragma unroll
        for (int n = 0; n < 2; ++n) {
            const bf16x8 bv = *(const bf16x8*)&Vls[(n * 16 + fr) * 264 + kk * 32 + fq * 8];
            o[n] = __builtin_amdgcn_mfma_f32_16x16x32_bf16(ap, bv, o[n], 0, 0, 0);
        }
    }
    float inv[4];
    #pragma unroll
    for (int r = 0; r < 4; ++r) inv[r] = 1.0f / sm[r];
    #pragma unroll
    for (int n = 0; n < 2; ++n)
        #pragma unroll
        for (int r = 0; r < 4; ++r)
            O[((long)(b * 2048 + n0 + w * 16 + fq * 4 + r)) * 256 + h * 32 + n * 16 + fr] =
                f2bf(o[n][r] * inv[r]);
}

// ---------------- final head ----------------
__global__ __launch_bounds__(256)
void out_kernel(const float* __restrict__ H, const float* __restrict__ Wout,
                const float* __restrict__ bout, float* __restrict__ out)
{
    const int row = blockIdx.x * 4 + (threadIdx.x >> 6);
    const int lane = threadIdx.x & 63;
    float4 hv = *(const float4*)&H[(long)row * 256 + lane * 4];
    float4 wv = *(const float4*)&Wout[lane * 4];
    float s = hv.x * wv.x + hv.y * wv.y + hv.z * wv.z + hv.w * wv.w;
    #pragma unroll
    for (int m = 32; m >= 1; m >>= 1) s += __shfl_xor(s, m);
    if (lane == 0) out[row] = s + bout[0];
}

extern "C" void kernel_launch(void* const* d_in, const int* in_sizes, int n_in,
                              void* d_out, int out_size, void* d_ws, size_t ws_size,
                              hipStream_t stream)
{
    const float* x    = (const float*)d_in[0];
    const float* Wemb = (const float*)d_in[1];
    const float* bemb = (const float*)d_in[2];
    const float* pos  = (const float*)d_in[3];
    const float* ln0g = (const float*)d_in[4];
    const float* ln0b = (const float*)d_in[5];
    const float* ln1g = (const float*)d_in[6];
    const float* ln1b = (const float*)d_in[7];
    const float* Wq   = (const float*)d_in[8];
    const float* Wk   = (const float*)d_in[9];
    const float* Wv   = (const float*)d_in[10];
    const float* Ek   = (const float*)d_in[11];
    const float* Ev   = (const float*)d_in[12];
    const float* Wo   = (const float*)d_in[13];
    const float* bo   = (const float*)d_in[14];
    const float* ln2g = (const float*)d_in[15];
    const float* ln2b = (const float*)d_in[16];
    const float* W1   = (const float*)d_in[17];
    const float* b1   = (const float*)d_in[18];
    const float* W2   = (const float*)d_in[19];
    const float* b2   = (const float*)d_in[20];
    const float* Wout = (const float*)d_in[21];
    const float* bout = (const float*)d_in[22];

    char* ws = (char*)d_ws;
    float*  h    = (float*)(ws + 0);                    // 33.5 MB
    ushort* abf  = (ushort*)(ws + 33554432L);           // 16.8 MB  [32768,256] bf16
    ushort* aT   = (ushort*)(ws + 50331648L);           // 16.8 MB  [16][256][2048] bf16
    ushort* qbf  = (ushort*)(ws + 67108864L);           // q bf16 [32768,256]
    ushort* apkv = (ushort*)(ws + 100663296L);          //  4.2 MB  [16][512][256] bf16
    ushort* kp   = (ushort*)(ws + 104857600L);          //  2.1 MB  [16][256][256] bf16 (row=key)
    ushort* vpT  = (ushort*)(ws + 109051904L);          //  2.1 MB  [16][256][256] bf16 (row=d)
    ushort* WT   = (ushort*)(ws + 113246208L);          // 14.7 MB
    ushort* WqT  = WT;
    ushort* WkT  = WT + 262144;
    ushort* WvT  = WT + 524288;
    ushort* WoT  = WT + 786432;
    ushort* W1T  = WT + 1048576;
    ushort* W2T  = WT + 2097152;
    ushort* EkvT = WT + 3145728;
    float* outp = (float*)d_out;

    transpose_cast<<<dim3(8, 8, 4), 256, 0, stream>>>(Wq, WqT, 256, 256, 65536, 65536);
    transpose_cast<<<dim3(8, 8, 4), 256, 0, stream>>>(Wk, WkT, 256, 256, 65536, 65536);
    transpose_cast<<<dim3(8, 8, 4), 256, 0, stream>>>(Wv, WvT, 256, 256, 65536, 65536);
    transpose_cast<<<dim3(8, 8, 4), 256, 0, stream>>>(Wo, WoT, 256, 256, 65536, 65536);
    transpose_cast<<<dim3(32, 8, 4), 256, 0, stream>>>(W1, W1T, 256, 1024, 262144, 262144);
    transpose_cast<<<dim3(8, 32, 4), 256, 0, stream>>>(W2, W2T, 1024, 256, 262144, 262144);
    transpose_cast<<<dim3(8, 64, 4), 256, 0, stream>>>(Ek, EkvT, 2048, 256, 524288, 1048576);
    transpose_cast<<<dim3(8, 64, 4), 256, 0, stream>>>(Ev, EkvT + 524288, 2048, 256, 524288, 1048576);

    embed_ln2<<<8192, 256, 0, stream>>>(x, Wemb, bemb, pos, ln0g, ln0b, h);

    for (int i = 0; i < 4; ++i) {
        const ushort* WqT_i = WqT + i * 65536;
        const ushort* WkT_i = WkT + i * 65536;
        const ushort* WvT_i = WvT + i * 65536;
        const ushort* WoT_i = WoT + i * 65536;
        const ushort* W1T_i = W1T + i * 262144;
        const ushort* W2T_i = W2T + i * 262144;
        const ushort* EkvT_i = EkvT + (long)i * 1048576;

        // a = LN1(h) -> bf16 ; aT = transpose(a)
        ln_kernel<<<8192, 256, 0, stream>>>(h, ln1g + i * 256, ln1b + i * 256, abf);
        transpose_act<<<dim3(8, 1024), 256, 0, stream>>>(abf, aT);
        // q = a @ Wq  (bf16 out)
        gemm_bf16<1,0,0,0><<<dim3(256, 2, 1), 256, 0, stream>>>(abf, WqT_i, nullptr, qbf,
            256, 256, 256, 256, 0, 0, 0);
        // apkv[b] = [Ek^T; Ev^T] @ a[b]  (bf16 out)
        gemm_bf16<1,0,0,0><<<dim3(4, 2, 16), 256, 0, stream>>>(EkvT_i, aT, nullptr, apkv,
            2048, 2048, 2048, 256, 0, 524288, 131072);
        // kp[b] = apk[b] @ Wk (bf16, row=key)
        gemm_bf16<1,0,0,0><<<dim3(2, 2, 16), 256, 0, stream>>>(apkv, WkT_i, nullptr, kp,
            256, 256, 256, 256, 131072, 0, 65536);
        // vpT[b] = Wv^T @ apv[b]^T  (bf16, row=d, col=key)
        gemm_bf16<1,0,0,0><<<dim3(2, 2, 16), 256, 0, stream>>>(WvT_i, apkv + 65536, nullptr, vpT,
            256, 256, 256, 256, 0, 131072, 65536);
        // fused MFMA attention -> abf (bf16)
        attn_mfma<<<dim3(32, 8, 16), 256, 0, stream>>>(qbf, kp, vpT, abf);
        // h += attnout @ Wo + bo
        gemm_bf16<0,1,0,1><<<dim3(256, 2, 1), 256, 0, stream>>>(abf, WoT_i, bo + i * 256, h,
            256, 256, 256, 256, 0, 0, 0);
        // h += gelu(LN2(h) @ W1 + b1) @ W2 + b2  (fused)
        ffn_fused<<<512, 256, 0, stream>>>(h, ln2g + i * 256, ln2b + i * 256,
            W1T_i, b1 + (long)i * 1024, W2T_i, b2 + i * 256);
    }
    out_kernel<<<8192, 256, 0, stream>>>(h, Wout, bout, outp);
}